// Round 4
// baseline (607.552 us; speedup 1.0000x reference)
//
#include <hip/hip_runtime.h>
#include <hip/hip_bf16.h>

namespace {

constexpr int NB = 4;          // batch
constexpr int CI = 2048;       // in channels
constexpr int CO = 1024;       // out channels
constexpr int HW = 4096;       // H*W
constexpr int MTOT = NB * HW;  // 16384 flattened rows

typedef __attribute__((ext_vector_type(8))) short bf16x8;
typedef __attribute__((ext_vector_type(4))) float f32x4;
typedef __hip_bfloat16 bf16;

__device__ __forceinline__ void g2l16(void* lds, const void* g) {
  __builtin_amdgcn_global_load_lds((const __attribute__((address_space(1))) void*)g,
                                   (__attribute__((address_space(3))) void*)lds,
                                   16, 0, 0);
}

__global__ void zero_k(float* __restrict__ p, int n) {
  int i = blockIdx.x * 256 + threadIdx.x;
  if (i < n) p[i] = 0.f;
}

// all six weight casts in one launch; y<3 are CI*CO, y>=3 are CO*CO; float4->ushort4
__global__ void castw6_k(const float* s0, const float* s1, const float* s2,
                         const float* s3, const float* s4, const float* s5,
                         bf16* d0, bf16* d1, bf16* d2, bf16* d3, bf16* d4, bf16* d5) {
  int y = blockIdx.y;
  const float* s = (y == 0) ? s0 : (y == 1) ? s1 : (y == 2) ? s2 : (y == 3) ? s3 : (y == 4) ? s4 : s5;
  bf16* d = (y == 0) ? d0 : (y == 1) ? d1 : (y == 2) ? d2 : (y == 3) ? d3 : (y == 4) ? d4 : d5;
  int n4 = ((y < 3) ? CI * CO : CO * CO) >> 2;
  int i = blockIdx.x * 256 + threadIdx.x;
  if (i < n4) {
    float4 v = ((const float4*)s)[i];
    union { ushort4 u; bf16 h[4]; } pk;
    pk.h[0] = __float2bfloat16(v.x);
    pk.h[1] = __float2bfloat16(v.y);
    pk.h[2] = __float2bfloat16(v.z);
    pk.h[3] = __float2bfloat16(v.w);
    ((ushort4*)d)[i] = pk.u;
  }
}

// dst[b,p] += sum over a 128-channel chunk of src[b,c,p]; grid (HW/256, CI/128, NB)
__global__ void nc_sum_k(const float* __restrict__ src, float* __restrict__ dst) {
  int p = blockIdx.x * 256 + threadIdx.x;
  int c0 = blockIdx.y * 128;
  int b = blockIdx.z;
  const float* s = src + ((long)b * CI + c0) * HW + p;
  float a = 0.f;
  #pragma unroll 8
  for (int c = 0; c < 128; ++c) a += s[(long)c * HW];
  atomicAdd(dst + b * HW + p, a);
}

template <typename T> __device__ __forceinline__ T cvt_out(float v);
template <> __device__ __forceinline__ float cvt_out<float>(float v) { return v; }
template <> __device__ __forceinline__ bf16 cvt_out<bf16>(float v) { return __float2bfloat16(v); }

// dst[b, s, r] = src[b, r, s];  grid (R/32, S/32, NB), block 256
template <typename TO>
__global__ void transpose_k(const float* __restrict__ src, TO* __restrict__ dst, int R, int S) {
  __shared__ float tile[32][33];
  int b = blockIdx.z;
  int r0 = blockIdx.x * 32, s0 = blockIdx.y * 32;
  int ts = threadIdx.x & 31, tr = threadIdx.x >> 5;   // tr 0..7
  const float* sp = src + ((long)b * R + r0) * S + s0;
  #pragma unroll
  for (int i = 0; i < 32; i += 8) tile[tr + i][ts] = sp[(long)(tr + i) * S + ts];
  __syncthreads();
  TO* dp = dst + ((long)b * S + s0) * R + r0;
  #pragma unroll
  for (int i = 0; i < 32; i += 8) dp[(long)(tr + i) * R + ts] = cvt_out<TO>(tile[ts][tr + i]);
}

// invden[b,p] = 1/(2048 * sum_{5x5} prev_nc)
__global__ void boxinv_k(const float* __restrict__ nc, float* __restrict__ invden) {
  int i = blockIdx.x * 256 + threadIdx.x;   // over NB*HW
  int b = i >> 12, p = i & 4095;
  int y = p >> 6, x = p & 63;
  float s = 0.f;
  #pragma unroll
  for (int dy = -2; dy <= 2; ++dy) {
    int yy = y + dy;
    if ((unsigned)yy >= 64u) continue;
    #pragma unroll
    for (int dx = -2; dx <= 2; ++dx) {
      int xx = x + dx;
      if ((unsigned)xx >= 64u) continue;
      s += nc[b * HW + yy * 64 + xx];
    }
  }
  invden[i] = 1.f / (2048.f * s);
}

// aligned (channels-last): f32 and bf16 copies. One block per (b,p); threads cover c in float4.
__global__ void align_k(const float* __restrict__ pmcl, const float* __restrict__ nc,
                        const float* __restrict__ invden, const int* __restrict__ body,
                        float* __restrict__ af, bf16* __restrict__ ah) {
  int bp = blockIdx.x;
  int b = bp >> 12, p = bp & 4095;
  int y = p >> 6, x = p & 63;
  int c = threadIdx.x * 4;
  float4 acc = make_float4(0.f, 0.f, 0.f, 0.f);
  if (body[0]) {
    #pragma unroll
    for (int dy = -2; dy <= 2; ++dy) {
      int yy = y + dy;
      if ((unsigned)yy >= 64u) continue;
      #pragma unroll
      for (int dx = -2; dx <= 2; ++dx) {
        int xx = x + dx;
        if ((unsigned)xx >= 64u) continue;
        int sp = yy * 64 + xx;
        float w = nc[b * HW + sp];
        float4 v = *(const float4*)(pmcl + ((long)b * HW + sp) * CO + c);
        acc.x += w * v.x; acc.y += w * v.y; acc.z += w * v.z; acc.w += w * v.w;
      }
    }
    float s = invden[bp];
    acc.x *= s; acc.y *= s; acc.z *= s; acc.w *= s;
  } else {
    acc = *(const float4*)(pmcl + (long)bp * CO + c);
  }
  long o = (long)bp * CO + c;
  *(float4*)(af + o) = acc;
  union { ushort4 u; bf16 h[4]; } pk;
  pk.h[0] = __float2bfloat16(acc.x);
  pk.h[1] = __float2bfloat16(acc.y);
  pk.h[2] = __float2bfloat16(acc.z);
  pk.h[3] = __float2bfloat16(acc.w);
  *(ushort4*)(ah + o) = pk.u;
}

// ---------------------------------------------------------------------------
// m201-style 8-phase GEMM: 256x256 tile, BK=64, 8 waves (2M x 4N, interleaved
// 16-row / 16-col wave stripes), 2 LDS buffers (2 x 64 KiB), 4 phases/K-tile.
// Phase = {ds_read one m-half x one k-slice (4 or 8 b128) | issue 2
// global_load_lds sub-blocks | barrier | setprio+16 MFMA+setprio | barrier}.
// One counted vmcnt(4) per K-tile (phase 4); staging runs 1.5 tiles ahead
// (12 loads in flight). Sub-block order per tile: #1=A[h0,k0] #2=B[h0,k0]
// #3=B[h1,k0] #4=A[h1,k0] #5=A[h0,k1] #6=B[h0,k1] #7=B[h1,k1] #8=A[h1,k1];
// #1-4 issued at P2,P3 of tile-2; #5-8 at P0,P1 of tile-1.
// LDS sub-region (matrix, kh): 128 lines x 128B, line = rows {2j,2j+1} x 32k,
// chunk slot swizzled by XOR(line&7); inverse applied to global source.
// C[p,o] = sum_k A1[p,k]B1[o,k] + sum_k A2[p,k]B2[o,k];  K1=2048, K2=1024.
// MODE 0: outf = relu(acc + b1 + b2)                              (zt)
// MODE 2: m = relu(acc + b1 + b2); outf = (1-zt)*alig + zt*m      (currM)
// MODE 3: rt = relu(acc + b1 + b2); outh = bf16(aligh * rt)       (ar)
// ---------------------------------------------------------------------------
template <int MODE>
__global__ __launch_bounds__(512, 2) void gemm8p(
    const bf16* __restrict__ A1, const bf16* __restrict__ B1,
    const bf16* __restrict__ A2, const bf16* __restrict__ B2,
    const float* __restrict__ bias1, const float* __restrict__ bias2,
    const float* __restrict__ ztp, const float* __restrict__ alig,
    const bf16* __restrict__ aligh,
    float* __restrict__ outf, bf16* __restrict__ outh) {
  constexpr int NT1 = CI / 64;        // 32
  constexpr int NT = NT1 + CO / 64;   // 48
  __shared__ __align__(16) char lds[131072];
  const int t = threadIdx.x, lane = t & 63, wid = t >> 6;
  const int wm = wid >> 2, wn = wid & 3;
  const int m0 = blockIdx.x * 256, n0 = blockIdx.y * 256;
  const int fr = lane & 15, kq = lane >> 4;

  // --- staging decode: thread t covers chunk t of each 8 KiB sub-block ---
  const int cc0 = (t & 7) ^ ((t >> 3) & 7);
  const int row_l = ((t >> 3) << 1) + (cc0 >> 2);   // 0..127
  const int k16 = cc0 & 3;                           // *8 elems in 32-k half
  const char* pa1 = (const char*)A1 + (((size_t)(m0 + row_l) * CI + k16 * 8) << 1);
  const char* pb1 = (const char*)B1 + (((size_t)(n0 + row_l) * CI + k16 * 8) << 1);
  const char* pa2 = (const char*)A2 + (((size_t)(m0 + row_l) * CO + k16 * 8) << 1);
  const char* pb2 = (const char*)B2 + (((size_t)(n0 + row_l) * CO + k16 * 8) << 1);

  auto ST = [&](int s, int isB, int rh, int kh) {
    const char* g;
    if (s < NT1) {
      g = (isB ? pb1 : pa1) + ((size_t)s << 7) + (kh << 6) + (rh ? 524288 : 0);
    } else {
      g = (isB ? pb2 : pa2) + ((size_t)(s - NT1) << 7) + (kh << 6) + (rh ? 262144 : 0);
    }
    g2l16(lds + ((s & 1) << 16) + (isB << 15) + (kh << 14) + (rh << 13) + (t << 4), g);
  };

  // --- fragment LDS read offsets (kh=0; kh=1 adds 16384) ---
  int offA[8], offB[4];
  #pragma unroll
  for (int m = 0; m < 8; ++m) {
    int r = wm * 16 + m * 32 + fr;
    int ln = r >> 1;
    int c = ((r & 1) << 2) | kq;
    offA[m] = (ln << 7) + ((c ^ (ln & 7)) << 4);
  }
  #pragma unroll
  for (int n = 0; n < 4; ++n) {
    int r = wn * 16 + n * 64 + fr;
    int ln = r >> 1;
    int c = ((r & 1) << 2) | kq;
    offB[n] = 32768 + (ln << 7) + ((c ^ (ln & 7)) << 4);
  }

  f32x4 acc[8][4] = {};
  bf16x8 av[4], bv[4];

  // prologue: tile0 (#1..#8) + tile1 (#1..#4); retire tile0, 4 in flight
  ST(0, 0, 0, 0); ST(0, 1, 0, 0); ST(0, 1, 1, 0); ST(0, 0, 1, 0);
  ST(0, 0, 0, 1); ST(0, 1, 0, 1); ST(0, 1, 1, 1); ST(0, 0, 1, 1);
  ST(1, 0, 0, 0); ST(1, 1, 0, 0); ST(1, 1, 1, 0); ST(1, 0, 1, 0);
  asm volatile("s_waitcnt vmcnt(4)" ::: "memory");
  __builtin_amdgcn_s_barrier();
  asm volatile("" ::: "memory");

#define BAR do { asm volatile("" ::: "memory"); __builtin_amdgcn_s_barrier(); \
                 asm volatile("" ::: "memory"); } while (0)
#define MFMA16(ACM)                                                           \
  __builtin_amdgcn_s_setprio(1);                                              \
  _Pragma("unroll") for (int mi_ = 0; mi_ < 4; ++mi_)                         \
  _Pragma("unroll") for (int ni_ = 0; ni_ < 4; ++ni_)                         \
    acc[(ACM) + mi_][ni_] = __builtin_amdgcn_mfma_f32_16x16x32_bf16(          \
        av[mi_], bv[ni_], acc[(ACM) + mi_][ni_], 0, 0, 0);                    \
  __builtin_amdgcn_s_setprio(0);

  #pragma unroll 1
  for (int s = 0; s < NT; ++s) {
    const char* buf = lds + ((s & 1) << 16);
    const bool st1 = (s + 1 < NT), st2 = (s + 2 < NT);
    // P0: m-half0, k0  (reads 8)  | stage #5,#6 of tile s+1
    #pragma unroll
    for (int i = 0; i < 4; ++i) av[i] = *(const bf16x8*)(buf + offA[i]);
    #pragma unroll
    for (int i = 0; i < 4; ++i) bv[i] = *(const bf16x8*)(buf + offB[i]);
    if (st1) { ST(s + 1, 0, 0, 1); ST(s + 1, 1, 0, 1); }
    BAR;
    MFMA16(0);
    BAR;
    // P1: m-half1, k0  (reads 4)  | stage #7,#8 of tile s+1
    #pragma unroll
    for (int i = 0; i < 4; ++i) av[i] = *(const bf16x8*)(buf + offA[4 + i]);
    if (st1) { ST(s + 1, 1, 1, 1); ST(s + 1, 0, 1, 1); }
    BAR;
    MFMA16(4);
    BAR;
    // P2: m-half0, k1  (reads 8)  | stage #1,#2 of tile s+2
    #pragma unroll
    for (int i = 0; i < 4; ++i) av[i] = *(const bf16x8*)(buf + 16384 + offA[i]);
    #pragma unroll
    for (int i = 0; i < 4; ++i) bv[i] = *(const bf16x8*)(buf + 16384 + offB[i]);
    if (st2) { ST(s + 2, 0, 0, 0); ST(s + 2, 1, 0, 0); }
    BAR;
    MFMA16(0);
    BAR;
    // P3: m-half1, k1  (reads 4)  | stage #3,#4 of tile s+2 | tile-boundary vmcnt
    #pragma unroll
    for (int i = 0; i < 4; ++i) av[i] = *(const bf16x8*)(buf + 16384 + offA[4 + i]);
    if (st2) { ST(s + 2, 1, 1, 0); ST(s + 2, 0, 1, 0); }
    BAR;
    MFMA16(4);
    if (s < NT - 2) asm volatile("s_waitcnt vmcnt(4)" ::: "memory");
    else            asm volatile("s_waitcnt vmcnt(0)" ::: "memory");
    BAR;
  }
#undef MFMA16
#undef BAR

  // --- epilogue ---
  #pragma unroll
  for (int mi = 0; mi < 8; ++mi) {
    const int r0 = m0 + wm * 16 + mi * 32 + kq * 4;
    #pragma unroll
    for (int ni = 0; ni < 4; ++ni) {
      const int col = n0 + wn * 16 + ni * 64 + fr;
      const float bsum = bias1[col] + bias2[col];
      #pragma unroll
      for (int j = 0; j < 4; ++j) {
        const size_t idx = (size_t)(r0 + j) * CO + col;
        float v = acc[mi][ni][j] + bsum;
        if (MODE == 0) {
          outf[idx] = fmaxf(v, 0.f);
        } else if (MODE == 3) {
          float rt = fmaxf(v, 0.f);
          outh[idx] = __float2bfloat16(__bfloat162float(aligh[idx]) * rt);
        } else {
          float m = fmaxf(v, 0.f);
          float z = ztp[idx];
          outf[idx] = (1.f - z) * alig[idx] + z * m;
        }
      }
    }
  }
}

}  // namespace

extern "C" void kernel_launch(void* const* d_in, const int* in_sizes, int n_in,
                              void* d_out, int out_size, void* d_ws, size_t ws_size,
                              hipStream_t stream) {
  const float* curr_F = (const float*)d_in[0];
  const float* prev_F = (const float*)d_in[1];
  const float* prev_M = (const float*)d_in[2];
  const float* Wz_w = (const float*)d_in[3];
  const float* Wz_b = (const float*)d_in[4];
  const float* Wr_w = (const float*)d_in[5];
  const float* Wr_b = (const float*)d_in[6];
  const float* W_w  = (const float*)d_in[7];
  const float* W_b  = (const float*)d_in[8];
  const float* Uz_w = (const float*)d_in[9];
  const float* Uz_b = (const float*)d_in[10];
  const float* Ur_w = (const float*)d_in[11];
  const float* Ur_b = (const float*)d_in[12];
  const float* U_w  = (const float*)d_in[13];
  const float* U_b  = (const float*)d_in[14];
  const int* body   = (const int*)d_in[15];
  float* out = (float*)d_out;

  char* ws = (char*)d_ws;
  const size_t M64 = 1ull << 26;  // 64 MiB
  const size_t M32 = 1ull << 25;  // 32 MiB
  // region0: currF bf16 cl (stays read-only through all GEMMs)
  bf16*  currF_h   = (bf16*)(ws);
  // region1: prevM f32 cl -> later zt f32 cl (prevM dead after align_k)
  float* prevM_cl  = (float*)(ws + M64);
  float* zt        = (float*)(ws + M64);
  float* align_f   = (float*)(ws + 2 * M64);
  bf16*  align_h   = (bf16*)(ws + 3 * M64);
  float* currM_cl  = (float*)(ws + 3 * M64 + M32);
  bf16*  ar_h      = (bf16*)(ws + 4 * M64 + M32);
  char*  wb        = ws + 4 * M64 + 2 * M32;
  bf16* Wz_h = (bf16*)wb;
  bf16* Wr_h = Wz_h + (size_t)CO * CI;
  bf16* W_h  = Wr_h + (size_t)CO * CI;
  bf16* Uz_h = W_h  + (size_t)CO * CI;
  bf16* Ur_h = Uz_h + (size_t)CO * CO;
  bf16* U_h  = Ur_h + (size_t)CO * CO;
  float* prev_nc = (float*)(U_h + (size_t)CO * CO);
  float* invden  = prev_nc + NB * HW;

  // weights -> bf16 (one launch)
  castw6_k<<<dim3((CI * CO) / 1024, 6), 256, 0, stream>>>(
      Wz_w, Wr_w, W_w, Uz_w, Ur_w, U_w, Wz_h, Wr_h, W_h, Uz_h, Ur_h, U_h);

  // prev_nc = sum_c prev_F
  zero_k<<<dim3((NB * HW) / 256), 256, 0, stream>>>(prev_nc, NB * HW);
  nc_sum_k<<<dim3(HW / 256, CI / 128, NB), 256, 0, stream>>>(prev_F, prev_nc);

  // transposes to channels-last
  transpose_k<bf16><<<dim3(CI / 32, HW / 32, NB), 256, 0, stream>>>(curr_F, currF_h, CI, HW);
  transpose_k<float><<<dim3(CO / 32, HW / 32, NB), 256, 0, stream>>>(prev_M, prevM_cl, CO, HW);

  boxinv_k<<<dim3((NB * HW) / 256), 256, 0, stream>>>(prev_nc, invden);
  align_k<<<dim3(NB * HW), 256, 0, stream>>>(prevM_cl, prev_nc, invden, body, align_f, align_h);

  dim3 gg(MTOT / 256, CO / 256);  // (64, 4) = 256 workgroups = 1/CU
  // zt = relu(Wz@curr + Uz@aligned + biases)   [bn_star is a no-op for B=4]
  gemm8p<0><<<gg, 512, 0, stream>>>(currF_h, Wz_h, align_h, Uz_h,
                                    Wz_b, Uz_b, nullptr, nullptr, nullptr, zt, nullptr);
  // ar = bf16(aligned * relu(Wr@curr + Ur@aligned + biases))
  gemm8p<3><<<gg, 512, 0, stream>>>(currF_h, Wr_h, align_h, Ur_h,
                                    Wr_b, Ur_b, nullptr, nullptr, align_h, nullptr, ar_h);
  // currM = (1-zt)*aligned + zt*relu(W@curr + U@ar + W_b + U_b)
  gemm8p<2><<<gg, 512, 0, stream>>>(currF_h, W_h, ar_h, U_h,
                                    W_b, U_b, zt, align_f, nullptr, currM_cl, nullptr);

  // [b,p,o] -> [b,o,p]
  transpose_k<float><<<dim3(HW / 32, CO / 32, NB), 256, 0, stream>>>(currM_cl, out, HW, CO);
}

// Round 5
// 554.454 us; speedup vs baseline: 1.0958x; 1.0958x over previous
//
#include <hip/hip_runtime.h>
#include <hip/hip_bf16.h>

namespace {

constexpr int NB = 4;          // batch
constexpr int CI = 2048;       // in channels
constexpr int CO = 1024;       // out channels
constexpr int HW = 4096;       // H*W
constexpr int MTOT = NB * HW;  // 16384 flattened rows

typedef __attribute__((ext_vector_type(8))) short bf16x8;
typedef __attribute__((ext_vector_type(4))) float f32x4;
typedef __hip_bfloat16 bf16;

__device__ __forceinline__ void g2l16(void* lds, const void* g) {
  __builtin_amdgcn_global_load_lds((const __attribute__((address_space(1))) void*)g,
                                   (__attribute__((address_space(3))) void*)lds,
                                   16, 0, 0);
}

__global__ void zero_k(float* __restrict__ p, int n) {
  int i = blockIdx.x * 256 + threadIdx.x;
  if (i < n) p[i] = 0.f;
}

// all six weight casts in one launch; y<3 are CI*CO, y>=3 are CO*CO; float4->ushort4
__global__ void castw6_k(const float* s0, const float* s1, const float* s2,
                         const float* s3, const float* s4, const float* s5,
                         bf16* d0, bf16* d1, bf16* d2, bf16* d3, bf16* d4, bf16* d5) {
  int y = blockIdx.y;
  const float* s = (y == 0) ? s0 : (y == 1) ? s1 : (y == 2) ? s2 : (y == 3) ? s3 : (y == 4) ? s4 : s5;
  bf16* d = (y == 0) ? d0 : (y == 1) ? d1 : (y == 2) ? d2 : (y == 3) ? d3 : (y == 4) ? d4 : d5;
  int n4 = ((y < 3) ? CI * CO : CO * CO) >> 2;
  int i = blockIdx.x * 256 + threadIdx.x;
  if (i < n4) {
    float4 v = ((const float4*)s)[i];
    union { ushort4 u; bf16 h[4]; } pk;
    pk.h[0] = __float2bfloat16(v.x);
    pk.h[1] = __float2bfloat16(v.y);
    pk.h[2] = __float2bfloat16(v.z);
    pk.h[3] = __float2bfloat16(v.w);
    ((ushort4*)d)[i] = pk.u;
  }
}

// dst[b,p] += sum over a 128-channel chunk of src[b,c,p]; grid (HW/256, CI/128, NB)
__global__ void nc_sum_k(const float* __restrict__ src, float* __restrict__ dst) {
  int p = blockIdx.x * 256 + threadIdx.x;
  int c0 = blockIdx.y * 128;
  int b = blockIdx.z;
  const float* s = src + ((long)b * CI + c0) * HW + p;
  float a = 0.f;
  #pragma unroll 8
  for (int c = 0; c < 128; ++c) a += s[(long)c * HW];
  atomicAdd(dst + b * HW + p, a);
}

template <typename T> __device__ __forceinline__ T cvt_out(float v);
template <> __device__ __forceinline__ float cvt_out<float>(float v) { return v; }
template <> __device__ __forceinline__ bf16 cvt_out<bf16>(float v) { return __float2bfloat16(v); }

// dst[b, s, r] = src[b, r, s];  grid (R/32, S/32, NB), block 256
template <typename TO>
__global__ void transpose_k(const float* __restrict__ src, TO* __restrict__ dst, int R, int S) {
  __shared__ float tile[32][33];
  int b = blockIdx.z;
  int r0 = blockIdx.x * 32, s0 = blockIdx.y * 32;
  int ts = threadIdx.x & 31, tr = threadIdx.x >> 5;   // tr 0..7
  const float* sp = src + ((long)b * R + r0) * S + s0;
  #pragma unroll
  for (int i = 0; i < 32; i += 8) tile[tr + i][ts] = sp[(long)(tr + i) * S + ts];
  __syncthreads();
  TO* dp = dst + ((long)b * S + s0) * R + r0;
  #pragma unroll
  for (int i = 0; i < 32; i += 8) dp[(long)(tr + i) * R + ts] = cvt_out<TO>(tile[ts][tr + i]);
}

// invden[b,p] = 1/(2048 * sum_{5x5} prev_nc)
__global__ void boxinv_k(const float* __restrict__ nc, float* __restrict__ invden) {
  int i = blockIdx.x * 256 + threadIdx.x;   // over NB*HW
  int b = i >> 12, p = i & 4095;
  int y = p >> 6, x = p & 63;
  float s = 0.f;
  #pragma unroll
  for (int dy = -2; dy <= 2; ++dy) {
    int yy = y + dy;
    if ((unsigned)yy >= 64u) continue;
    #pragma unroll
    for (int dx = -2; dx <= 2; ++dx) {
      int xx = x + dx;
      if ((unsigned)xx >= 64u) continue;
      s += nc[b * HW + yy * 64 + xx];
    }
  }
  invden[i] = 1.f / (2048.f * s);
}

// aligned (channels-last, bf16). One block per (b,p); threads cover c in float4.
__global__ void align_k(const float* __restrict__ pmcl, const float* __restrict__ nc,
                        const float* __restrict__ invden, const int* __restrict__ body,
                        bf16* __restrict__ ah) {
  int bp = blockIdx.x;
  int b = bp >> 12, p = bp & 4095;
  int y = p >> 6, x = p & 63;
  int c = threadIdx.x * 4;
  float4 acc = make_float4(0.f, 0.f, 0.f, 0.f);
  if (body[0]) {
    #pragma unroll
    for (int dy = -2; dy <= 2; ++dy) {
      int yy = y + dy;
      if ((unsigned)yy >= 64u) continue;
      #pragma unroll
      for (int dx = -2; dx <= 2; ++dx) {
        int xx = x + dx;
        if ((unsigned)xx >= 64u) continue;
        int sp = yy * 64 + xx;
        float w = nc[b * HW + sp];
        float4 v = *(const float4*)(pmcl + ((long)b * HW + sp) * CO + c);
        acc.x += w * v.x; acc.y += w * v.y; acc.z += w * v.z; acc.w += w * v.w;
      }
    }
    float s = invden[bp];
    acc.x *= s; acc.y *= s; acc.z *= s; acc.w *= s;
  } else {
    acc = *(const float4*)(pmcl + (long)bp * CO + c);
  }
  union { ushort4 u; bf16 h[4]; } pk;
  pk.h[0] = __float2bfloat16(acc.x);
  pk.h[1] = __float2bfloat16(acc.y);
  pk.h[2] = __float2bfloat16(acc.z);
  pk.h[3] = __float2bfloat16(acc.w);
  *(ushort4*)(ah + (long)bp * CO + c) = pk.u;
}

// ---------------------------------------------------------------------------
// 256x256-tile dual-K GEMM, 8 waves (2Mx4N), 4-deep ring of BK=32 subtiles,
// monolithic phases (R2 schedule: best measured), swizzled LDS (T2, 0
// conflicts), counted vmcnt(12) (T4), setprio (T5).
// C[p,o] = sum_k A1[p,k]B1[o,k] + sum_k A2[p,k]B2[o,k];  K1=2048, K2=1024.
// ldA1=ldB1=CI, ldA2=ldB2=CO for all modes.
// MODE 0: zt[p,o]   = relu(acc + b1 + b2)                   (f32, chan-last)
// MODE 3: ar[p,o]   = bf16(aligh * relu(acc + b1 + b2))     (bf16, chan-last)
// MODE 2: m = relu(acc + b1 + b2);
//         out[b,o,p] = (1-zt)*aligh + zt*m                  (f32, chan-FIRST,
//         float4 over 4 consecutive p -> no separate transpose kernel)
// ---------------------------------------------------------------------------
template <int MODE>
__global__ __launch_bounds__(512, 2) void gemm256(
    const bf16* __restrict__ A1, const bf16* __restrict__ B1,
    const bf16* __restrict__ A2, const bf16* __restrict__ B2,
    const float* __restrict__ bias1, const float* __restrict__ bias2,
    const float* __restrict__ ztp, const bf16* __restrict__ aligh,
    float* __restrict__ outf, bf16* __restrict__ outh,
    float* __restrict__ outcf) {
  constexpr int NT1 = CI / 32;        // 64
  constexpr int NT = NT1 + CO / 32;   // 96
  __shared__ __align__(16) char lds[131072];
  const int t = threadIdx.x, lane = t & 63, wid = t >> 6;
  const int wm = wid >> 2, wn = wid & 3;
  const int m0 = blockIdx.x * 256, n0 = blockIdx.y * 256;
  const int fr = lane & 15, kq = lane >> 4;

  // --- staging source precompute (inverse swizzle on global address) ---
  const int b0i = (wid << 7) + lane;
  const int line0 = b0i >> 3;
  const int c3 = (b0i & 7) ^ (line0 & 7);
  const int row0 = 2 * line0 + (c3 >> 2);
  const int k16 = c3 & 3;
  const char* pa1 = (const char*)A1 + (((size_t)(m0 + row0) * CI + k16 * 8) << 1);
  const char* pa1h = pa1 + ((size_t)CI << 5);   // +16 rows
  const char* pb1 = (const char*)B1 + (((size_t)(n0 + row0) * CI + k16 * 8) << 1);
  const char* pb1h = pb1 + ((size_t)CI << 5);
  const char* pa2 = (const char*)A2 + (((size_t)(m0 + row0) * CO + k16 * 8) << 1);
  const char* pa2h = pa2 + ((size_t)CO << 5);
  const char* pb2 = (const char*)B2 + (((size_t)(n0 + row0) * CO + k16 * 8) << 1);
  const char* pb2h = pb2 + ((size_t)CO << 5);

  auto STAGE = [&](int s) {
    const char *sa, *sah, *sb, *sbh;
    if (s < NT1) {
      size_t so = (size_t)s << 6;
      sa = pa1 + so; sah = pa1h + so; sb = pb1 + so; sbh = pb1h + so;
    } else {
      size_t so = (size_t)(s - NT1) << 6;
      sa = pa2 + so; sah = pa2h + so; sb = pb2 + so; sbh = pb2h + so;
    }
    char* d = lds + ((s & 3) << 15) + (wid << 11) + (lane << 4);
    g2l16(d, sa);
    g2l16(d + 1024, sah);
    g2l16(d + 16384, sb);
    g2l16(d + 17408, sbh);
  };

  // --- fragment LDS read offsets (swizzled), loop-invariant ---
  int offA[8], offB[4];
  #pragma unroll
  for (int mi = 0; mi < 8; ++mi) {
    int r = (wm << 7) + (mi << 4) + fr;
    int ln = r >> 1;
    int cc = ((r & 1) << 2) | kq;
    offA[mi] = (ln << 7) + ((cc ^ (ln & 7)) << 4);
  }
  #pragma unroll
  for (int ni = 0; ni < 4; ++ni) {
    int r = (wn << 6) + (ni << 4) + fr;
    int ln = r >> 1;
    int cc = ((r & 1) << 2) | kq;
    offB[ni] = 16384 + (ln << 7) + ((cc ^ (ln & 7)) << 4);
  }

  f32x4 acc[8][4] = {};

  STAGE(0); STAGE(1); STAGE(2);

  auto PHASE = [&](int tp, int W, bool dostage) {
    if (dostage) STAGE(tp + 3);
    if (W == 12)      asm volatile("s_waitcnt vmcnt(12)" ::: "memory");
    else if (W == 8)  asm volatile("s_waitcnt vmcnt(8)" ::: "memory");
    else if (W == 4)  asm volatile("s_waitcnt vmcnt(4)" ::: "memory");
    else              asm volatile("s_waitcnt vmcnt(0)" ::: "memory");
    __builtin_amdgcn_s_barrier();
    asm volatile("" ::: "memory");   // keep ds_reads below the barrier
    const char* buf = lds + ((tp & 3) << 15);
    bf16x8 av[8], bv[4];
    #pragma unroll
    for (int mi = 0; mi < 8; ++mi) av[mi] = *(const bf16x8*)(buf + offA[mi]);
    #pragma unroll
    for (int ni = 0; ni < 4; ++ni) bv[ni] = *(const bf16x8*)(buf + offB[ni]);
    __builtin_amdgcn_s_setprio(1);
    #pragma unroll
    for (int mi = 0; mi < 8; ++mi)
      #pragma unroll
      for (int ni = 0; ni < 4; ++ni)
        acc[mi][ni] = __builtin_amdgcn_mfma_f32_16x16x32_bf16(av[mi], bv[ni], acc[mi][ni], 0, 0, 0);
    __builtin_amdgcn_s_setprio(0);
    asm volatile("" ::: "memory");   // keep ds_reads above the barrier
    __builtin_amdgcn_s_barrier();    // frees buf[tp&3] for next phase's STAGE
  };

  #pragma unroll 1
  for (int tt = 0; tt < NT - 3; ++tt) PHASE(tt, 12, true);
  PHASE(NT - 3, 8, false);
  PHASE(NT - 2, 4, false);
  PHASE(NT - 1, 0, false);

  // --- epilogue ---
  #pragma unroll
  for (int mi = 0; mi < 8; ++mi) {
    const int r0 = m0 + (wm << 7) + (mi << 4) + (kq << 2);
    #pragma unroll
    for (int ni = 0; ni < 4; ++ni) {
      const int col = n0 + (wn << 6) + (ni << 4) + fr;
      const float bsum = bias1[col] + bias2[col];
      if (MODE == 2) {
        // channels-first float4 write: 4 consecutive p at fixed (b, col)
        const int bb = r0 >> 12, p0 = r0 & 4095;
        float4 o;
        float* po = &o.x;
        #pragma unroll
        for (int j = 0; j < 4; ++j) {
          const size_t idx = (size_t)(r0 + j) * CO + col;   // channels-last idx
          float m = fmaxf(acc[mi][ni][j] + bsum, 0.f);
          float z = ztp[idx];
          float a = __bfloat162float(aligh[idx]);
          po[j] = (1.f - z) * a + z * m;
        }
        *(float4*)(outcf + ((size_t)bb * CO + col) * HW + p0) = o;
      } else {
        #pragma unroll
        for (int j = 0; j < 4; ++j) {
          const size_t idx = (size_t)(r0 + j) * CO + col;
          float v = acc[mi][ni][j] + bsum;
          if (MODE == 0) {
            outf[idx] = fmaxf(v, 0.f);
          } else {  // MODE 3
            float rt = fmaxf(v, 0.f);
            outh[idx] = __float2bfloat16(__bfloat162float(aligh[idx]) * rt);
          }
        }
      }
    }
  }
}

}  // namespace

extern "C" void kernel_launch(void* const* d_in, const int* in_sizes, int n_in,
                              void* d_out, int out_size, void* d_ws, size_t ws_size,
                              hipStream_t stream) {
  const float* curr_F = (const float*)d_in[0];
  const float* prev_F = (const float*)d_in[1];
  const float* prev_M = (const float*)d_in[2];
  const float* Wz_w = (const float*)d_in[3];
  const float* Wz_b = (const float*)d_in[4];
  const float* Wr_w = (const float*)d_in[5];
  const float* Wr_b = (const float*)d_in[6];
  const float* W_w  = (const float*)d_in[7];
  const float* W_b  = (const float*)d_in[8];
  const float* Uz_w = (const float*)d_in[9];
  const float* Uz_b = (const float*)d_in[10];
  const float* Ur_w = (const float*)d_in[11];
  const float* Ur_b = (const float*)d_in[12];
  const float* U_w  = (const float*)d_in[13];
  const float* U_b  = (const float*)d_in[14];
  const int* body   = (const int*)d_in[15];
  float* out = (float*)d_out;

  char* ws = (char*)d_ws;
  const size_t M64 = 1ull << 26;  // 64 MiB
  const size_t M32 = 1ull << 25;  // 32 MiB
  // region0: currF bf16 cl (read-only through all GEMMs)
  bf16*  currF_h   = (bf16*)(ws);
  // region1: prevM f32 cl -> later zt f32 cl (prevM dead after align_k)
  float* prevM_cl  = (float*)(ws + M64);
  float* zt        = (float*)(ws + M64);
  bf16*  align_h   = (bf16*)(ws + 2 * M64);
  bf16*  ar_h      = (bf16*)(ws + 2 * M64 + M32);
  char*  wb        = ws + 2 * M64 + 2 * M32;
  bf16* Wz_h = (bf16*)wb;
  bf16* Wr_h = Wz_h + (size_t)CO * CI;
  bf16* W_h  = Wr_h + (size_t)CO * CI;
  bf16* Uz_h = W_h  + (size_t)CO * CI;
  bf16* Ur_h = Uz_h + (size_t)CO * CO;
  bf16* U_h  = Ur_h + (size_t)CO * CO;
  float* prev_nc = (float*)(U_h + (size_t)CO * CO);
  float* invden  = prev_nc + NB * HW;

  // weights -> bf16 (one launch)
  castw6_k<<<dim3((CI * CO) / 1024, 6), 256, 0, stream>>>(
      Wz_w, Wr_w, W_w, Uz_w, Ur_w, U_w, Wz_h, Wr_h, W_h, Uz_h, Ur_h, U_h);

  // prev_nc = sum_c prev_F
  zero_k<<<dim3((NB * HW) / 256), 256, 0, stream>>>(prev_nc, NB * HW);
  nc_sum_k<<<dim3(HW / 256, CI / 128, NB), 256, 0, stream>>>(prev_F, prev_nc);

  // transposes to channels-last
  transpose_k<bf16><<<dim3(CI / 32, HW / 32, NB), 256, 0, stream>>>(curr_F, currF_h, CI, HW);
  transpose_k<float><<<dim3(CO / 32, HW / 32, NB), 256, 0, stream>>>(prev_M, prevM_cl, CO, HW);

  boxinv_k<<<dim3((NB * HW) / 256), 256, 0, stream>>>(prev_nc, invden);
  align_k<<<dim3(NB * HW), 256, 0, stream>>>(prevM_cl, prev_nc, invden, body, align_h);

  dim3 gg(MTOT / 256, CO / 256);  // (64, 4) = 256 workgroups = 1/CU
  // zt = relu(Wz@curr + Uz@aligned + biases)   [bn_star is a no-op for B=4]
  gemm256<0><<<gg, 512, 0, stream>>>(currF_h, Wz_h, align_h, Uz_h,
                                     Wz_b, Uz_b, nullptr, nullptr, zt, nullptr, nullptr);
  // ar = bf16(aligned * relu(Wr@curr + Ur@aligned + biases))
  gemm256<3><<<gg, 512, 0, stream>>>(currF_h, Wr_h, align_h, Ur_h,
                                     Wr_b, Ur_b, nullptr, align_h, nullptr, ar_h, nullptr);
  // out[b,o,p] = (1-zt)*aligned + zt*relu(W@curr + U@ar + W_b + U_b)
  gemm256<2><<<gg, 512, 0, stream>>>(currF_h, W_h, ar_h, U_h,
                                     W_b, U_b, zt, align_h, nullptr, nullptr, out);
}